// Round 11
// baseline (48.059 us; speedup 1.0000x reference)
//
#include <hip/hip_runtime.h>

#define HW   4096
#define CIN  32
// scale in log2 domain: (1/sqrt(NCLASS)) * log2(e); NCLASS = 2
#define SCALE2 (0.70710678118654752f * 1.44269504088896340f)

// Raw v_exp_f32 (2^x): args bounded (|x| <~ 12), skip libm denormal fixup.
__device__ __forceinline__ float exp2_raw(float x) {
#if __has_builtin(__builtin_amdgcn_exp2f)
    return __builtin_amdgcn_exp2f(x);
#else
    float r;
    asm("v_exp_f32 %0, %1" : "=v"(r) : "v"(x));
    return r;
#endif
}

// ---------------- Kernel 1: proj + rowstats fused.
// block = (n, 64 p's), 1024 threads, 256 blocks (1/CU).
//   phase 0a: f2 for ALL 4096 q of batch n -> LDS (32 KB); one block per batch
//             also publishes f2v globally for kernel 2.
//   phase 0b: f1 (scaled) for our 64 p's -> LDS.
//   phase 1:  B-loop from LDS: l[p] = sum_q 2^(f1[p].f2[q]);
//             write stats4 {f1x*s, f1y*s, V0/l, V1/l}.
__global__ __launch_bounds__(1024, 4) void rowstats_fused(
        const float* __restrict__ feat, const float* __restrict__ outv,
        const float* __restrict__ w1, const float* __restrict__ b1,
        const float* __restrict__ w2, const float* __restrict__ b2,
        float2* __restrict__ f2v, float4* __restrict__ stats4) {
    __shared__ float4 sf2[2048];       // f2 of all 4096 q, as q-pairs (32 KB)
    __shared__ float2 sf1[64];         // scaled f1 of our 64 p's
    __shared__ float  partial[16][16]; // [wave][p-local&15]

    int tid = threadIdx.x;
    int lane = tid & 63;
    int w = tid >> 6;                  // 16 waves
    int b = blockIdx.x;                // 256 blocks
    int n = b >> 6;
    int pg = (b & 63) << 6;            // 64 p's
    int base = n * HW;
    const float* fb = feat + (size_t)n * CIN * HW;

    // ---- phase 0a: f2 for all q (4 q per thread, q = tid + 1024k) ----
    {
        float a0[4] = {0.f, 0.f, 0.f, 0.f};
        float a1[4] = {0.f, 0.f, 0.f, 0.f};
        for (int c = 0; c < CIN; ++c) {
            float wa = w2[c], wb = w2[CIN + c];
            const float* fc = fb + (size_t)c * HW + tid;
#pragma unroll
            for (int k = 0; k < 4; ++k) {
                float v = fc[k << 10];
                a0[k] += v * wa;
                a1[k] += v * wb;
            }
        }
        float2* sf2f = (float2*)sf2;
        bool pub = (b & 63) == 0;      // one block per batch publishes f2v
#pragma unroll
        for (int k = 0; k < 4; ++k) {
            float2 val = make_float2(a0[k] + b2[0], a1[k] + b2[1]);
            sf2f[(k << 10) + tid] = val;
            if (pub) f2v[base + (k << 10) + tid] = val;
        }
    }
    // ---- phase 0b: scaled f1 for our 64 p's (threads 0..127) ----
    if (tid < 128) {
        int p = pg + (tid & 63);
        int ch = tid >> 6;
        float s = 0.f;
        for (int c = 0; c < CIN; ++c) s += fb[(size_t)c * HW + p] * w1[ch * CIN + c];
        ((float*)&sf1[tid & 63])[ch] = (s + b1[ch]) * SCALE2;
    }
    __syncthreads();

    // ---- phase 1: B-loop from LDS. wave w: p-group w>>2, q-slice w&3 ----
    {
        int pgrp = (w >> 2) << 4;      // p-local base (16 p's)
        float f10[16], f11[16];
#pragma unroll
        for (int j = 0; j < 16; ++j) { // uniform LDS addr -> broadcast
            float2 t = sf1[pgrp + j];
            f10[j] = t.x; f11[j] = t.y;
        }
        const float4* sp = sf2 + ((w & 3) << 9) + lane;
        float v[16];
#pragma unroll
        for (int j = 0; j < 16; ++j) v[j] = 0.f;
#pragma unroll
        for (int s = 0; s < 8; ++s) {
            float4 ab = sp[s * 64];    // ds_read_b128, conflict-free
#pragma unroll
            for (int j = 0; j < 16; ++j) {
                float e0 = exp2_raw(f10[j] * ab.x + f11[j] * ab.y);
                float e1 = exp2_raw(f10[j] * ab.z + f11[j] * ab.w);
                v[j] += e0 + e1;
            }
        }
        // recursive-halving exchange: lane ends holding idx = lane&15
        bool up8 = lane & 8;
#pragma unroll
        for (int k = 0; k < 8; ++k) {
            float send = up8 ? v[k] : v[k + 8];
            float recv = __shfl_xor(send, 8);
            v[k] = (up8 ? v[k + 8] : v[k]) + recv;
        }
        bool up4 = lane & 4;
#pragma unroll
        for (int k = 0; k < 4; ++k) {
            float send = up4 ? v[k] : v[k + 4];
            float recv = __shfl_xor(send, 4);
            v[k] = (up4 ? v[k + 4] : v[k]) + recv;
        }
        bool up2 = lane & 2;
#pragma unroll
        for (int k = 0; k < 2; ++k) {
            float send = up2 ? v[k] : v[k + 2];
            float recv = __shfl_xor(send, 2);
            v[k] = (up2 ? v[k + 2] : v[k]) + recv;
        }
        bool up1 = lane & 1;
        {
            float send = up1 ? v[0] : v[1];
            float recv = __shfl_xor(send, 1);
            v[0] = (up1 ? v[1] : v[0]) + recv;
        }
        v[0] += __shfl_xor(v[0], 16);
        v[0] += __shfl_xor(v[0], 32);
        if (lane < 16) partial[w][lane] = v[0];
    }
    __syncthreads();
    if (tid < 64) {
        int g4 = (tid >> 4) << 2;      // p-group's 4 q-slice waves
        int j = tid & 15;
        float l = partial[g4][j] + partial[g4 + 1][j]
                + partial[g4 + 2][j] + partial[g4 + 3][j];
        float inv = 1.0f / l;
        float2 f1 = sf1[tid];          // scaled
        int pp = pg + tid;
        float v0 = outv[(n * 2 + 0) * HW + pp];
        float v1 = outv[(n * 2 + 1) * HW + pp];
        stats4[base + pp] = make_float4(f1.x, f1.y, v0 * inv, v1 * inv);
    }
}

// ---------------- Kernel 2: o[c,q] = sum_p (V[c,p]/l[p]) * 2^(f1[p].f2[q]*s)
// (round-10 colout, verbatim)
__global__ __launch_bounds__(256) void colout_kernel(
        const float2* __restrict__ f2v, const float4* __restrict__ stats4,
        float* __restrict__ o) {
    __shared__ float pC[4][33];        // padded: bank-safe cross-wave partials
    int tid = threadIdx.x;
    int lane = tid & 63;
    int wid = tid >> 6;
    int b = blockIdx.x;                // 1024 blocks
    int n = b >> 8;
    int qg = (b & 255) << 4;           // 16 q's
    int base = n * HW;

    int ub = __builtin_amdgcn_readfirstlane(base + qg);
    float g0[16], g1[16];
#pragma unroll
    for (int j = 0; j < 16; ++j) {     // uniform -> s_load (SCALE2 folded in stats4)
        float2 f2 = f2v[ub + j];
        g0[j] = f2.x;
        g1[j] = f2.y;
    }
    const float4* stb = stats4 + base + wid * 1024 + lane;
    // value layout: v[j] = (ch0, q j), v[16+j] = (ch1, q j)  -> idx = ch*16+q
    float v[32];
#pragma unroll
    for (int j = 0; j < 32; ++j) v[j] = 0.f;
    float4 cur = stb[0];
#pragma unroll
    for (int s = 0; s < 16; ++s) {
        float4 nxt = stb[((s + 1) & 15) * 64];  // distance-1 rotation, const offsets
#pragma unroll
        for (int j = 0; j < 16; ++j) {
            float e = exp2_raw(g0[j] * cur.x + g1[j] * cur.y);
            v[j]      += cur.z * e;
            v[16 + j] += cur.w * e;
        }
        cur = nxt;
    }
    // recursive-halving exchange over 32 values: lane ends holding idx = lane&31
    {
        bool up16 = lane & 16;
#pragma unroll
        for (int k = 0; k < 16; ++k) {
            float send = up16 ? v[k] : v[k + 16];
            float recv = __shfl_xor(send, 16);
            v[k] = (up16 ? v[k + 16] : v[k]) + recv;
        }
        bool up8 = lane & 8;
#pragma unroll
        for (int k = 0; k < 8; ++k) {
            float send = up8 ? v[k] : v[k + 8];
            float recv = __shfl_xor(send, 8);
            v[k] = (up8 ? v[k + 8] : v[k]) + recv;
        }
        bool up4 = lane & 4;
#pragma unroll
        for (int k = 0; k < 4; ++k) {
            float send = up4 ? v[k] : v[k + 4];
            float recv = __shfl_xor(send, 4);
            v[k] = (up4 ? v[k + 4] : v[k]) + recv;
        }
        bool up2 = lane & 2;
#pragma unroll
        for (int k = 0; k < 2; ++k) {
            float send = up2 ? v[k] : v[k + 2];
            float recv = __shfl_xor(send, 2);
            v[k] = (up2 ? v[k + 2] : v[k]) + recv;
        }
        bool up1 = lane & 1;
        {
            float send = up1 ? v[0] : v[1];
            float recv = __shfl_xor(send, 1);
            v[0] = (up1 ? v[1] : v[0]) + recv;
        }
        v[0] += __shfl_xor(v[0], 32);
    }
    if (lane < 32) pC[wid][lane] = v[0];
    __syncthreads();
    if (tid < 32) {
        float r = pC[0][tid] + pC[1][tid] + pC[2][tid] + pC[3][tid];
        int ch = tid >> 4, qq = tid & 15;
        o[(n * 2 + ch) * HW + qg + qq] = r;
    }
}

extern "C" void kernel_launch(void* const* d_in, const int* in_sizes, int n_in,
                              void* d_out, int out_size, void* d_ws, size_t ws_size,
                              hipStream_t stream) {
    const float* feat = (const float*)d_in[0];   // (4,32,64,64)
    const float* outv = (const float*)d_in[1];   // (4,2,64,64)
    const float* w1   = (const float*)d_in[2];   // (2,32)
    const float* b1   = (const float*)d_in[3];   // (2,)
    const float* w2   = (const float*)d_in[4];   // (2,32)
    const float* b2   = (const float*)d_in[5];   // (2,)
    float* o = (float*)d_out;                    // (4,2,64,64)

    // workspace layout (384 KB used):
    float*  ws     = (float*)d_ws;
    float2* f2v    = (float2*)ws;                // 16384 float2 = 128 KB
    float4* stats4 = (float4*)(ws + 32768);      // 16384 float4 = 256 KB

    rowstats_fused<<<256, 1024, 0, stream>>>(feat, outv, w1, b1, w2, b2, f2v, stats4);
    colout_kernel<<<1024, 256, 0, stream>>>(f2v, stats4, o);
}

// Round 12
// 33.987 us; speedup vs baseline: 1.4140x; 1.4140x over previous
//
#include <hip/hip_runtime.h>

#define HW   4096
#define CIN  32
// scale in log2 domain: (1/sqrt(NCLASS)) * log2(e); NCLASS = 2
#define SCALE2 (0.70710678118654752f * 1.44269504088896340f)

// Raw v_exp_f32 (2^x): args bounded (|x| <~ 12), skip libm denormal fixup.
__device__ __forceinline__ float exp2_raw(float x) {
#if __has_builtin(__builtin_amdgcn_exp2f)
    return __builtin_amdgcn_exp2f(x);
#else
    float r;
    asm("v_exp_f32 %0, %1" : "=v"(r) : "v"(x));
    return r;
#endif
}

// ---------------- Kernel A: 1x1 conv projections, channel-split 4-way across waves
__global__ __launch_bounds__(256) void proj_kernel(
        const float* __restrict__ feat,
        const float* __restrict__ w1, const float* __restrict__ b1,
        const float* __restrict__ w2, const float* __restrict__ b2,
        float2* __restrict__ f1v, float2* __restrict__ f2v) {
    __shared__ float4 red[4][64];
    int tid = threadIdx.x;
    int pl = tid & 63;
    int cq = tid >> 6;                 // wave id = channel quarter
    int b = blockIdx.x;                // 256 blocks
    int n = b >> 6;
    int p = ((b & 63) << 6) + pl;
    const float* fbase = feat + ((size_t)n * CIN + cq * 8) * HW + p;
    float a10 = 0.f, a11 = 0.f, a20 = 0.f, a21 = 0.f;
#pragma unroll
    for (int c = 0; c < 8; ++c) {
        float v = fbase[(size_t)c * HW];
        a10 += v * w1[cq * 8 + c];
        a11 += v * w1[32 + cq * 8 + c];
        a20 += v * w2[cq * 8 + c];
        a21 += v * w2[32 + cq * 8 + c];
    }
    red[cq][pl] = make_float4(a10, a11, a20, a21);
    __syncthreads();
    if (tid < 64) {
        float4 r0 = red[0][tid], r1 = red[1][tid], r2 = red[2][tid], r3 = red[3][tid];
        int idx = n * HW + ((b & 63) << 6) + tid;
        f1v[idx] = make_float2(r0.x + r1.x + r2.x + r3.x + b1[0],
                               r0.y + r1.y + r2.y + r3.y + b1[1]);
        f2v[idx] = make_float2(r0.z + r1.z + r2.z + r3.z + b2[0],
                               r0.w + r1.w + r2.w + r3.w + b2[1]);
    }
}

// ---------------- Kernel B: l[p] = sum_q 2^(f1[p].f2[q]*s); write {f1*s, V0/l, V1/l}
// block = (n, 8 p's), 2048 blocks (8/CU); f1 via readfirstlane base -> SGPRs.
// wave wid streams its q-quarter as float4 (2 q/entry), coalesced, depth-4 prefetch.
__global__ __launch_bounds__(256, 8) void rowstats_kernel(
        const float2* __restrict__ f1v, const float2* __restrict__ f2v,
        const float* __restrict__ outv, float4* __restrict__ stats4) {
    __shared__ float pB[4][9];
    int tid = threadIdx.x;
    int lane = tid & 63;
    int wid = tid >> 6;
    int b = blockIdx.x;                // 2048 blocks
    int n = b >> 9;
    int pg = (b & 511) << 3;           // 8 p's
    int base = n * HW;

    int ub = __builtin_amdgcn_readfirstlane(base + pg);
    float f10[8], f11[8];
#pragma unroll
    for (int j = 0; j < 8; ++j) {      // uniform base -> s_loads, SGPR-resident
        float2 f1 = f1v[ub + j];
        f10[j] = f1.x * SCALE2;
        f11[j] = f1.y * SCALE2;
    }
    const float4* f2b = (const float4*)(f2v + base) + wid * 512 + lane;
    float v[8];
#pragma unroll
    for (int j = 0; j < 8; ++j) v[j] = 0.f;
    float4 buf[4];
#pragma unroll
    for (int k = 0; k < 4; ++k) buf[k] = f2b[k * 64];   // 4 loads in flight
#pragma unroll
    for (int s = 0; s < 8; ++s) {
        float4 cur = buf[s & 3];
        if (s + 4 < 8) buf[s & 3] = f2b[(s + 4) * 64];  // keep depth 4
#pragma unroll
        for (int j = 0; j < 8; ++j) {
            float e0 = exp2_raw(f10[j] * cur.x + f11[j] * cur.y);
            float e1 = exp2_raw(f10[j] * cur.z + f11[j] * cur.w);
            v[j] += e0 + e1;
        }
    }
    // recursive-halving exchange: lane ends holding idx = lane&7
    {
        bool up4 = lane & 4;
#pragma unroll
        for (int k = 0; k < 4; ++k) {
            float send = up4 ? v[k] : v[k + 4];
            float recv = __shfl_xor(send, 4);
            v[k] = (up4 ? v[k + 4] : v[k]) + recv;
        }
        bool up2 = lane & 2;
#pragma unroll
        for (int k = 0; k < 2; ++k) {
            float send = up2 ? v[k] : v[k + 2];
            float recv = __shfl_xor(send, 2);
            v[k] = (up2 ? v[k + 2] : v[k]) + recv;
        }
        bool up1 = lane & 1;
        {
            float send = up1 ? v[0] : v[1];
            float recv = __shfl_xor(send, 1);
            v[0] = (up1 ? v[1] : v[0]) + recv;
        }
        v[0] += __shfl_xor(v[0], 8);
        v[0] += __shfl_xor(v[0], 16);
        v[0] += __shfl_xor(v[0], 32);
    }
    if (lane < 8) pB[wid][lane] = v[0];
    __syncthreads();
    if (tid < 8) {
        float lt = pB[0][tid] + pB[1][tid] + pB[2][tid] + pB[3][tid];
        float inv = 1.0f / lt;
        int pp = pg + tid;
        float2 f1 = f1v[base + pp];
        float v0 = outv[(n * 2 + 0) * HW + pp];
        float v1 = outv[(n * 2 + 1) * HW + pp];
        stats4[base + pp] = make_float4(f1.x * SCALE2, f1.y * SCALE2, v0 * inv, v1 * inv);
    }
}

// ---------------- Kernel C: o[c,q] = sum_p (V[c,p]/l[p]) * 2^(f1[p].f2[q]*s)
// block = (n, 8 q's), 2048 blocks (8/CU); g via readfirstlane base -> SGPRs.
// wave wid streams its p-quarter of stats4, coalesced, depth-4 prefetch.
__global__ __launch_bounds__(256, 8) void colout_kernel(
        const float2* __restrict__ f2v, const float4* __restrict__ stats4,
        float* __restrict__ o) {
    __shared__ float pC[4][17];
    int tid = threadIdx.x;
    int lane = tid & 63;
    int wid = tid >> 6;
    int b = blockIdx.x;                // 2048 blocks
    int n = b >> 9;
    int qg = (b & 511) << 3;           // 8 q's
    int base = n * HW;

    int ub = __builtin_amdgcn_readfirstlane(base + qg);
    float g0[8], g1[8];
#pragma unroll
    for (int j = 0; j < 8; ++j) {      // uniform base -> s_loads, SGPR-resident
        float2 f2 = f2v[ub + j];
        g0[j] = f2.x;
        g1[j] = f2.y;
    }
    const float4* stb = stats4 + base + wid * 1024 + lane;
    // value layout: v[j] = (ch0, q j), v[8+j] = (ch1, q j) -> idx = ch*8+q
    float v[16];
#pragma unroll
    for (int j = 0; j < 16; ++j) v[j] = 0.f;
    float4 buf[4];
#pragma unroll
    for (int k = 0; k < 4; ++k) buf[k] = stb[k * 64];   // 4 loads in flight
#pragma unroll
    for (int s = 0; s < 16; ++s) {
        float4 cur = buf[s & 3];
        if (s + 4 < 16) buf[s & 3] = stb[(s + 4) * 64]; // keep depth 4
#pragma unroll
        for (int j = 0; j < 8; ++j) {
            float e = exp2_raw(g0[j] * cur.x + g1[j] * cur.y);
            v[j]     += cur.z * e;
            v[8 + j] += cur.w * e;
        }
    }
    // recursive-halving exchange over 16 values: lane ends holding idx = lane&15
    {
        bool up8 = lane & 8;
#pragma unroll
        for (int k = 0; k < 8; ++k) {
            float send = up8 ? v[k] : v[k + 8];
            float recv = __shfl_xor(send, 8);
            v[k] = (up8 ? v[k + 8] : v[k]) + recv;
        }
        bool up4 = lane & 4;
#pragma unroll
        for (int k = 0; k < 4; ++k) {
            float send = up4 ? v[k] : v[k + 4];
            float recv = __shfl_xor(send, 4);
            v[k] = (up4 ? v[k + 4] : v[k]) + recv;
        }
        bool up2 = lane & 2;
#pragma unroll
        for (int k = 0; k < 2; ++k) {
            float send = up2 ? v[k] : v[k + 2];
            float recv = __shfl_xor(send, 2);
            v[k] = (up2 ? v[k + 2] : v[k]) + recv;
        }
        bool up1 = lane & 1;
        {
            float send = up1 ? v[0] : v[1];
            float recv = __shfl_xor(send, 1);
            v[0] = (up1 ? v[1] : v[0]) + recv;
        }
        v[0] += __shfl_xor(v[0], 16);
        v[0] += __shfl_xor(v[0], 32);
    }
    if (lane < 16) pC[wid][lane] = v[0];
    __syncthreads();
    if (tid < 16) {
        float r = pC[0][tid] + pC[1][tid] + pC[2][tid] + pC[3][tid];
        int ch = tid >> 3, qq = tid & 7;
        o[(n * 2 + ch) * HW + qg + qq] = r;
    }
}

extern "C" void kernel_launch(void* const* d_in, const int* in_sizes, int n_in,
                              void* d_out, int out_size, void* d_ws, size_t ws_size,
                              hipStream_t stream) {
    const float* feat = (const float*)d_in[0];   // (4,32,64,64)
    const float* outv = (const float*)d_in[1];   // (4,2,64,64)
    const float* w1   = (const float*)d_in[2];   // (2,32)
    const float* b1   = (const float*)d_in[3];   // (2,)
    const float* w2   = (const float*)d_in[4];   // (2,32)
    const float* b2   = (const float*)d_in[5];   // (2,)
    float* o = (float*)d_out;                    // (4,2,64,64)

    // workspace layout (512 KB used):
    float*  ws     = (float*)d_ws;
    float2* f1v    = (float2*)ws;                // 16384 float2 = 128 KB
    float2* f2v    = (float2*)(ws + 32768);      // 16384 float2 = 128 KB
    float4* stats4 = (float4*)(ws + 65536);      // 16384 float4 = 256 KB

    proj_kernel<<<256, 256, 0, stream>>>(feat, w1, b1, w2, b2, f1v, f2v);
    rowstats_kernel<<<2048, 256, 0, stream>>>(f1v, f2v, outv, stats4);
    colout_kernel<<<2048, 256, 0, stream>>>(f2v, stats4, o);
}